// Round 1
// baseline (1045.898 us; speedup 1.0000x reference)
//
#include <hip/hip_runtime.h>
#include <stdint.h>

#define NN 8192
#define DD 128

typedef __attribute__((ext_vector_type(4))) float floatx4;
typedef __attribute__((ext_vector_type(8))) short s16x8;
typedef __attribute__((ext_vector_type(8))) unsigned short u16x8;
typedef __attribute__((ext_vector_type(4))) unsigned short u16x4;

__device__ inline unsigned short f32_bf16(float f) {
    union { float f; uint32_t u; } v; v.f = f;
    uint32_t u = v.u;
    return (unsigned short)((u + 0x7FFFu + ((u >> 16) & 1u)) >> 16);
}

// ---------------------------------------------------------------------------
// convert_tile: src fp32 [R][C] -> dstT bf16 [C][R] (transposed), and
// optionally dstN bf16 [R][C]. Tile 64x64, block=256.
// ---------------------------------------------------------------------------
__global__ __launch_bounds__(256) void convert_tile(const float* __restrict__ src,
        unsigned short* __restrict__ dstT, unsigned short* __restrict__ dstN,
        int R, int C) {
    __shared__ __align__(16) unsigned short lt[64][72];
    int r0 = blockIdx.x * 64, c0 = blockIdx.y * 64;
    int t = threadIdx.x;
    int row = t >> 2, seg = t & 3;          // 4 threads/row, 16 cols each
    const float* sp = src + (size_t)(r0 + row) * C + c0 + seg * 16;
    unsigned short v[16];
#pragma unroll
    for (int i = 0; i < 4; ++i) {
        floatx4 f = *(const floatx4*)(sp + i * 4);
#pragma unroll
        for (int e = 0; e < 4; ++e) v[i * 4 + e] = f32_bf16(f[e]);
    }
#pragma unroll
    for (int i = 0; i < 16; ++i) lt[seg * 16 + i][row] = v[i];
    if (dstN) {
        u16x8 p0, p1;
#pragma unroll
        for (int i = 0; i < 8; ++i) { p0[i] = v[i]; p1[i] = v[8 + i]; }
        unsigned short* dp = dstN + (size_t)(r0 + row) * C + c0 + seg * 16;
        *(u16x8*)dp = p0;
        *(u16x8*)(dp + 8) = p1;
    }
    __syncthreads();
    int cc = t >> 2, s2 = t & 3;
    u16x8 a = *(const u16x8*)(&lt[cc][s2 * 16]);
    u16x8 b = *(const u16x8*)(&lt[cc][s2 * 16 + 8]);
    unsigned short* dp = dstT + (size_t)(c0 + cc) * R + r0 + s2 * 16;
    *(u16x8*)dp = a;
    *(u16x8*)(dp + 8) = b;
}

// ---------------------------------------------------------------------------
// rowsum of fp32 [NN][NN] -> out[NN]
// ---------------------------------------------------------------------------
__global__ __launch_bounds__(256) void rowsum_f32(const float* __restrict__ a,
                                                  float* __restrict__ out) {
    int row = blockIdx.x, t = threadIdx.x;
    const float* p = a + (size_t)row * NN;
    float s = 0.f;
#pragma unroll
    for (int i = 0; i < NN / 4; i += 256) {
        floatx4 f = *(const floatx4*)(p + (size_t)(i + t) * 4);
        s += f[0] + f[1] + f[2] + f[3];
    }
#pragma unroll
    for (int off = 32; off > 0; off >>= 1) s += __shfl_down(s, off, 64);
    __shared__ float red[4];
    if ((t & 63) == 0) red[t >> 6] = s;
    __syncthreads();
    if (t == 0) out[row] = red[0] + red[1] + red[2] + red[3];
}

// colsum of fp32 [NN][NN] -> out[NN] (out must be zeroed first)
__global__ __launch_bounds__(256) void colsum_f32(const float* __restrict__ a,
                                                  float* __restrict__ out) {
    int c = blockIdx.x * 256 + threadIdx.x;
    int r0 = blockIdx.y * 512;
    float s = 0.f;
    for (int r = 0; r < 512; ++r) s += a[(size_t)(r0 + r) * NN + c];
    atomicAdd(&out[c], s);
}

// ---------------------------------------------------------------------------
// gemm_big: Ypart[bz][m][n] = A[m, kslice] @ B[kslice, n]
//   A: AMODE 0: bf16 row-major [m][k]   (ld = NN)
//      AMODE 1: fp32 row-major [m][k]   (convert in staging)
//      AMODE 2: fp32 [k][m] (transposed staging; slow fallback)
//   B: always bf16 transposed layout Bt[n=128][k=NN]
// split-K = 8 (blockIdx.y), BM=128, BK=64, block=256 (4 waves, 2x2).
// ---------------------------------------------------------------------------
template <int AMODE>
__global__ __launch_bounds__(256, 2) void gemm_big(const void* __restrict__ Av,
        const unsigned short* __restrict__ Bt, float* __restrict__ Ypart) {
    __shared__ __align__(16) unsigned short LA[128 * 72];
    __shared__ __align__(16) unsigned short LB[128 * 72];
    int m0 = blockIdx.x * 128;
    int kbase = blockIdx.y * (NN / 8);
    int t = threadIdx.x;
    int wid = t >> 6, lane = t & 63;
    int wy = wid >> 1, wx = wid & 1;
    int l15 = lane & 15, l4 = lane >> 4;
    floatx4 acc[4][4] = {};

    for (int kt = 0; kt < NN / 8; kt += 64) {
        int k0 = kbase + kt;
        if (AMODE == 0) {
            const unsigned short* A16 = (const unsigned short*)Av;
            int m = t >> 3, kk = (t & 7) * 8;
#pragma unroll
            for (int s = 0; s < 4; ++s) {
                int mm = m + s * 32;
                u16x8 d = *(const u16x8*)(A16 + (size_t)(m0 + mm) * NN + k0 + kk);
                *(u16x8*)(&LA[mm * 72 + kk]) = d;
            }
        } else if (AMODE == 1) {
            const float* A32 = (const float*)Av;
            int m = t >> 4, kk = (t & 15) * 4;
#pragma unroll
            for (int s = 0; s < 8; ++s) {
                int mm = m + s * 16;
                floatx4 f = *(const floatx4*)(A32 + (size_t)(m0 + mm) * NN + k0 + kk);
                u16x4 pk;
#pragma unroll
                for (int e = 0; e < 4; ++e) pk[e] = f32_bf16(f[e]);
                *(u16x4*)(&LA[mm * 72 + kk]) = pk;
            }
        } else {
            const float* A32 = (const float*)Av;
            int kr = t >> 5, mm = (t & 31) * 4;
#pragma unroll
            for (int s = 0; s < 8; ++s) {
                int kk = kr + s * 8;
                floatx4 f = *(const floatx4*)(A32 + (size_t)(k0 + kk) * NN + m0 + mm);
#pragma unroll
                for (int e = 0; e < 4; ++e) LA[(mm + e) * 72 + kk] = f32_bf16(f[e]);
            }
        }
        {
            int n = t >> 3, kk = (t & 7) * 8;
#pragma unroll
            for (int s = 0; s < 4; ++s) {
                int nn = n + s * 32;
                u16x8 d = *(const u16x8*)(Bt + (size_t)nn * NN + k0 + kk);
                *(u16x8*)(&LB[nn * 72 + kk]) = d;
            }
        }
        __syncthreads();
#pragma unroll
        for (int ks = 0; ks < 2; ++ks) {
            s16x8 af[4], bfr[4];
#pragma unroll
            for (int i = 0; i < 4; ++i) {
                int m = wy * 64 + i * 16 + l15;
                af[i] = *(const s16x8*)(&LA[m * 72 + ks * 32 + l4 * 8]);
                int n = wx * 64 + i * 16 + l15;
                bfr[i] = *(const s16x8*)(&LB[n * 72 + ks * 32 + l4 * 8]);
            }
#pragma unroll
            for (int i = 0; i < 4; ++i)
#pragma unroll
                for (int j = 0; j < 4; ++j)
                    acc[i][j] = __builtin_amdgcn_mfma_f32_16x16x32_bf16(
                        af[i], bfr[j], acc[i][j], 0, 0, 0);
        }
        __syncthreads();
    }
    float* Y = Ypart + (size_t)blockIdx.y * ((size_t)NN * DD);
#pragma unroll
    for (int i = 0; i < 4; ++i)
#pragma unroll
        for (int j = 0; j < 4; ++j) {
            int col = wx * 64 + j * 16 + l15;
#pragma unroll
            for (int r = 0; r < 4; ++r) {
                int row = wy * 64 + i * 16 + l4 * 4 + r;
                Y[(size_t)(m0 + row) * DD + col] = acc[i][j][r];
            }
        }
}

// ---------------------------------------------------------------------------
// gemm_small: Z[m][n] = (sum_s Ypart[s][m][:]) @ W  * (1/sums[m])
//   writes out32 fp32 [NN][DD] (if non-null) and/or outT bf16 [DD][NN].
// BM=64, k=128 (one staged tile), grid = NN/64 = 128, block=256.
// ---------------------------------------------------------------------------
__global__ __launch_bounds__(256) void gemm_small(const float* __restrict__ Ypart,
        const unsigned short* __restrict__ Wt, const float* __restrict__ sums,
        float* __restrict__ out32, unsigned short* __restrict__ outT) {
    __shared__ __align__(16) unsigned short LA[64 * 136];
    __shared__ __align__(16) unsigned short LB[128 * 136];
    int m0 = blockIdx.x * 64;
    int t = threadIdx.x;
    {
        int m = t >> 5, kk = (t & 31) * 4;
#pragma unroll
        for (int s8 = 0; s8 < 8; ++s8) {
            int mm = m + s8 * 8;
            floatx4 sum = {0.f, 0.f, 0.f, 0.f};
#pragma unroll
            for (int s = 0; s < 8; ++s)
                sum += *(const floatx4*)(Ypart + (size_t)s * ((size_t)NN * DD) +
                                         (size_t)(m0 + mm) * DD + kk);
            u16x4 pk;
#pragma unroll
            for (int e = 0; e < 4; ++e) pk[e] = f32_bf16(sum[e]);
            *(u16x4*)(&LA[mm * 136 + kk]) = pk;
        }
        int n = t >> 4, k8 = (t & 15) * 8;
#pragma unroll
        for (int s = 0; s < 8; ++s) {
            int nn = n + s * 16;
            *(u16x8*)(&LB[nn * 136 + k8]) = *(const u16x8*)(Wt + nn * 128 + k8);
        }
    }
    __syncthreads();
    int wid = t >> 6, lane = t & 63;
    int wy = wid >> 1, wx = wid & 1, l15 = lane & 15, l4 = lane >> 4;
    floatx4 acc[2][4] = {};
#pragma unroll
    for (int ks = 0; ks < 4; ++ks) {
        s16x8 af[2], bfr[4];
#pragma unroll
        for (int i = 0; i < 2; ++i)
            af[i] = *(const s16x8*)(&LA[(wy * 32 + i * 16 + l15) * 136 + ks * 32 + l4 * 8]);
#pragma unroll
        for (int j = 0; j < 4; ++j)
            bfr[j] = *(const s16x8*)(&LB[(wx * 64 + j * 16 + l15) * 136 + ks * 32 + l4 * 8]);
#pragma unroll
        for (int i = 0; i < 2; ++i)
#pragma unroll
            for (int j = 0; j < 4; ++j)
                acc[i][j] = __builtin_amdgcn_mfma_f32_16x16x32_bf16(
                    af[i], bfr[j], acc[i][j], 0, 0, 0);
    }
#pragma unroll
    for (int i = 0; i < 2; ++i)
#pragma unroll
        for (int j = 0; j < 4; ++j) {
            int col = wx * 64 + j * 16 + l15;
#pragma unroll
            for (int r = 0; r < 4; ++r) {
                int row = wy * 32 + i * 16 + l4 * 4 + r;
                int m = m0 + row;
                float val = acc[i][j][r] / sums[m];
                if (out32) out32[(size_t)m * DD + col] = val;
                if (outT) outT[(size_t)col * NN + m] = f32_bf16(val);
            }
        }
}

// ---------------------------------------------------------------------------
extern "C" void kernel_launch(void* const* d_in, const int* in_sizes, int n_in,
                              void* d_out, int out_size, void* d_ws, size_t ws_size,
                              hipStream_t stream) {
    const float* adj = (const float*)d_in[0];
    const float* uni = (const float*)d_in[1];
    const float* sub = (const float*)d_in[2];
    const float* ws1 = (const float*)d_in[3];
    const float* wu1 = (const float*)d_in[4];
    float* out = (float*)d_out;

    const size_t SZ_A16 = (size_t)NN * NN * 2;       // 128 MiB
    const size_t SZ_Y   = (size_t)8 * NN * DD * 4;   // 32 MiB (8 split-K slices)
    const size_t SZ_F   = (size_t)NN * DD * 2;       // 2 MiB
    const size_t SZ_W   = (size_t)128 * 128 * 2;
    const size_t SZ_V   = (size_t)NN * 4;

    size_t needA = 2 * SZ_A16 + SZ_Y + 6 * SZ_F + 2 * SZ_W + 2 * SZ_V;
    size_t needB = 1 * SZ_A16 + SZ_Y + 6 * SZ_F + 2 * SZ_W + 2 * SZ_V;
    int tier = (ws_size >= needA) ? 0 : ((ws_size >= needB) ? 1 : 2);

    char* p = (char*)d_ws;
    unsigned short* A16 = nullptr;
    unsigned short* AT16 = nullptr;
    if (tier == 0) { A16 = (unsigned short*)p; p += SZ_A16; }
    if (tier <= 1) { AT16 = (unsigned short*)p; p += SZ_A16; }
    float* Ypart = (float*)p; p += SZ_Y;
    unsigned short* F[6];
    for (int i = 0; i < 6; ++i) { F[i] = (unsigned short*)p; p += SZ_F; }
    unsigned short* Wst = (unsigned short*)p; p += SZ_W;
    unsigned short* Wut = (unsigned short*)p; p += SZ_W;
    float* rsum = (float*)p; p += SZ_V;
    float* csum = (float*)p; p += SZ_V;

    // --- preprocessing ---
    if (tier == 0)
        convert_tile<<<dim3(128, 128), 256, 0, stream>>>(adj, AT16, A16, NN, NN);
    else if (tier == 1)
        convert_tile<<<dim3(128, 128), 256, 0, stream>>>(adj, AT16, nullptr, NN, NN);
    rowsum_f32<<<NN, 256, 0, stream>>>(adj, rsum);
    hipMemsetAsync(csum, 0, SZ_V, stream);
    colsum_f32<<<dim3(32, 16), 256, 0, stream>>>(adj, csum);
    convert_tile<<<dim3(128, 2), 256, 0, stream>>>(uni, F[0], nullptr, NN, DD); // U0t
    convert_tile<<<dim3(128, 2), 256, 0, stream>>>(sub, F[1], nullptr, NN, DD); // S0t
    convert_tile<<<dim3(2, 2), 256, 0, stream>>>(ws1, Wst, nullptr, DD, DD);
    convert_tile<<<dim3(2, 2), 256, 0, stream>>>(wu1, Wut, nullptr, DD, DD);

    unsigned short* Ut[3] = {F[0], F[3], F[5]};
    unsigned short* St[3] = {F[1], F[2], F[4]};

    for (int pass = 0; pass < 3; ++pass) {
        // G2: Ys = adjT @ U_prev  (normalize by colsum, then @ w_s1)
        if (tier <= 1)
            gemm_big<0><<<dim3(64, 8), 256, 0, stream>>>(AT16, Ut[pass], Ypart);
        else
            gemm_big<2><<<dim3(64, 8), 256, 0, stream>>>(adj, Ut[pass], Ypart);
        if (pass < 2)
            gemm_small<<<128, 256, 0, stream>>>(Ypart, Wst, csum, nullptr, St[pass + 1]);
        else
            gemm_small<<<128, 256, 0, stream>>>(Ypart, Wst, csum, out, nullptr);

        // G1: Yu = adj @ S_prev  (normalize by rowsum, then @ w_u1)
        if (tier == 0)
            gemm_big<0><<<dim3(64, 8), 256, 0, stream>>>(A16, St[pass], Ypart);
        else
            gemm_big<1><<<dim3(64, 8), 256, 0, stream>>>(adj, St[pass], Ypart);
        if (pass < 2)
            gemm_small<<<128, 256, 0, stream>>>(Ypart, Wut, rsum, nullptr, Ut[pass + 1]);
        else
            gemm_small<<<128, 256, 0, stream>>>(Ypart, Wut, rsum, out + (size_t)NN * DD, nullptr);
    }
}

// Round 2
// 748.697 us; speedup vs baseline: 1.3970x; 1.3970x over previous
//
#include <hip/hip_runtime.h>
#include <stdint.h>

#define NN 8192
#define DD 128

typedef __attribute__((ext_vector_type(4))) float floatx4;
typedef __attribute__((ext_vector_type(8))) short s16x8;
typedef __attribute__((ext_vector_type(8))) unsigned short u16x8;
typedef __attribute__((ext_vector_type(4))) unsigned short u16x4;

__device__ inline unsigned short f32_bf16(float f) {
    union { float f; uint32_t u; } v; v.f = f;
    uint32_t u = v.u;
    return (unsigned short)((u + 0x7FFFu + ((u >> 16) & 1u)) >> 16);
}

// ---------------------------------------------------------------------------
// convert_fused: src fp32 [R][C] ->
//   dstT bf16 [C][R] (transposed)   if dstT != null
//   dstN bf16 [R][C]                if dstN != null
//   rsum[r] += row sums (fp32)      if rsum != null   (atomic)
//   csum[c] += col sums (fp32)      if csum != null   (atomic)
// Tile 64x64, block=256 (t = ty*16+tx; lane owns a 4x4 sub-block).
// ---------------------------------------------------------------------------
__global__ __launch_bounds__(256) void convert_fused(const float* __restrict__ src,
        unsigned short* __restrict__ dstT, unsigned short* __restrict__ dstN,
        int R, int C, float* __restrict__ rsum, float* __restrict__ csum) {
    __shared__ __align__(16) unsigned short lt[64 * 68];
    __shared__ float colbuf[64];
    int r0 = blockIdx.x * 64, c0 = blockIdx.y * 64;
    int t = threadIdx.x, tx = t & 15, ty = t >> 4;
    if (csum && t < 64) colbuf[t] = 0.f;

    const float* sp = src + (size_t)(r0 + ty * 4) * C + c0 + tx * 4;
    float f[4][4];
#pragma unroll
    for (int i = 0; i < 4; ++i) {
        floatx4 v = *(const floatx4*)(sp + (size_t)i * C);
        f[i][0] = v[0]; f[i][1] = v[1]; f[i][2] = v[2]; f[i][3] = v[3];
    }
    if (dstN) {
#pragma unroll
        for (int i = 0; i < 4; ++i) {
            u16x4 pk;
#pragma unroll
            for (int j = 0; j < 4; ++j) pk[j] = f32_bf16(f[i][j]);
            *(u16x4*)(dstN + (size_t)(r0 + ty * 4 + i) * C + c0 + tx * 4) = pk;
        }
    }
    if (rsum) {
#pragma unroll
        for (int i = 0; i < 4; ++i) {
            float s = (f[i][0] + f[i][1]) + (f[i][2] + f[i][3]);
            s += __shfl_down(s, 8, 16);
            s += __shfl_down(s, 4, 16);
            s += __shfl_down(s, 2, 16);
            s += __shfl_down(s, 1, 16);
            if (tx == 0) atomicAdd(&rsum[r0 + ty * 4 + i], s);
        }
    }
    __syncthreads();   // colbuf init visible
    if (csum) {
#pragma unroll
        for (int j = 0; j < 4; ++j) {
            float s = (f[0][j] + f[1][j]) + (f[2][j] + f[3][j]);
            s += __shfl_down(s, 32);
            s += __shfl_down(s, 16);
            if (((t >> 4) & 3) == 0) atomicAdd(&colbuf[tx * 4 + j], s);
        }
    }
    if (dstT) {
#pragma unroll
        for (int j = 0; j < 4; ++j) {
            u16x4 pk;
#pragma unroll
            for (int i = 0; i < 4; ++i) pk[i] = f32_bf16(f[i][j]);
            *(u16x4*)(&lt[(tx * 4 + j) * 68 + ty * 4]) = pk;
        }
    }
    __syncthreads();
    if (csum && t < 64) atomicAdd(&csum[c0 + t], colbuf[t]);
    if (dstT) {
        int cc = t >> 2, seg = t & 3;
        u16x4 q0 = *(const u16x4*)(&lt[cc * 68 + seg * 16]);
        u16x4 q1 = *(const u16x4*)(&lt[cc * 68 + seg * 16 + 4]);
        u16x4 q2 = *(const u16x4*)(&lt[cc * 68 + seg * 16 + 8]);
        u16x4 q3 = *(const u16x4*)(&lt[cc * 68 + seg * 16 + 12]);
        u16x8 o0, o1;
#pragma unroll
        for (int e = 0; e < 4; ++e) { o0[e] = q0[e]; o0[4 + e] = q1[e];
                                      o1[e] = q2[e]; o1[4 + e] = q3[e]; }
        unsigned short* dp = dstT + (size_t)(c0 + cc) * R + r0 + seg * 16;
        *(u16x8*)dp = o0;
        *(u16x8*)(dp + 8) = o1;
    }
}

// ---------------------------------------------------------------------------
// gemm_big_bf16: Ypart[bz][m][n] = A[m, kslice] @ B[kslice, n]
//   A bf16 row-major [m][k] (ld=NN), B bf16 transposed Bt[n=128][k=NN].
// split-K = 8 (blockIdx.y), BM=128, BK=64, block=256 (4 waves, 2x2).
// Register-pipelined: tile k+1 global loads issued before the MFMA block of
// tile k (vmcnt wait lands at the next LDS store, overlapping loads w/ MFMA).
// ---------------------------------------------------------------------------
__global__ __launch_bounds__(256, 2) void gemm_big_bf16(
        const unsigned short* __restrict__ A16,
        const unsigned short* __restrict__ Bt, float* __restrict__ Ypart) {
    __shared__ __align__(16) unsigned short LA[128 * 72];
    __shared__ __align__(16) unsigned short LB[128 * 72];
    int m0 = blockIdx.x * 128;
    int kbase = blockIdx.y * (NN / 8);
    int t = threadIdx.x;
    int wid = t >> 6, lane = t & 63;
    int wy = wid >> 1, wx = wid & 1;
    int l15 = lane & 15, l4 = lane >> 4;
    int sm = t >> 3, sk = (t & 7) * 8;
    const unsigned short* ap = A16 + (size_t)(m0 + sm) * NN + kbase + sk;
    const unsigned short* bp = Bt + (size_t)sm * NN + kbase + sk;
    floatx4 acc[4][4] = {};
    u16x8 ra[4], rb[4];

#pragma unroll
    for (int s = 0; s < 4; ++s) {
        ra[s] = *(const u16x8*)(ap + (size_t)(s * 32) * NN);
        rb[s] = *(const u16x8*)(bp + (size_t)(s * 32) * NN);
    }
    for (int kt = 0; kt < 16; ++kt) {
#pragma unroll
        for (int s = 0; s < 4; ++s) {
            *(u16x8*)(&LA[(sm + s * 32) * 72 + sk]) = ra[s];
            *(u16x8*)(&LB[(sm + s * 32) * 72 + sk]) = rb[s];
        }
        __syncthreads();
        if (kt < 15) {
            int off = (kt + 1) * 64;
#pragma unroll
            for (int s = 0; s < 4; ++s) {
                ra[s] = *(const u16x8*)(ap + (size_t)(s * 32) * NN + off);
                rb[s] = *(const u16x8*)(bp + (size_t)(s * 32) * NN + off);
            }
        }
#pragma unroll
        for (int ks = 0; ks < 2; ++ks) {
            s16x8 af[4], bfr[4];
#pragma unroll
            for (int i = 0; i < 4; ++i) {
                int m = wy * 64 + i * 16 + l15;
                af[i] = *(const s16x8*)(&LA[m * 72 + ks * 32 + l4 * 8]);
                int n = wx * 64 + i * 16 + l15;
                bfr[i] = *(const s16x8*)(&LB[n * 72 + ks * 32 + l4 * 8]);
            }
#pragma unroll
            for (int i = 0; i < 4; ++i)
#pragma unroll
                for (int j = 0; j < 4; ++j)
                    acc[i][j] = __builtin_amdgcn_mfma_f32_16x16x32_bf16(
                        af[i], bfr[j], acc[i][j], 0, 0, 0);
        }
        __syncthreads();
    }
    float* Y = Ypart + (size_t)blockIdx.y * ((size_t)NN * DD);
#pragma unroll
    for (int i = 0; i < 4; ++i)
#pragma unroll
        for (int j = 0; j < 4; ++j) {
            int col = wx * 64 + j * 16 + l15;
#pragma unroll
            for (int r = 0; r < 4; ++r) {
                int row = wy * 64 + i * 16 + l4 * 4 + r;
                Y[(size_t)(m0 + row) * DD + col] = acc[i][j][r];
            }
        }
}

// ---------------------------------------------------------------------------
// gemm_big fallback (fp32 source), AMODE 1: fp32 row-major; AMODE 2: fp32
// [k][m] transposed staging. Only used when workspace is too small.
// ---------------------------------------------------------------------------
template <int AMODE>
__global__ __launch_bounds__(256, 2) void gemm_big(const void* __restrict__ Av,
        const unsigned short* __restrict__ Bt, float* __restrict__ Ypart) {
    __shared__ __align__(16) unsigned short LA[128 * 72];
    __shared__ __align__(16) unsigned short LB[128 * 72];
    int m0 = blockIdx.x * 128;
    int kbase = blockIdx.y * (NN / 8);
    int t = threadIdx.x;
    int wid = t >> 6, lane = t & 63;
    int wy = wid >> 1, wx = wid & 1;
    int l15 = lane & 15, l4 = lane >> 4;
    floatx4 acc[4][4] = {};

    for (int kt = 0; kt < NN / 8; kt += 64) {
        int k0 = kbase + kt;
        if (AMODE == 1) {
            const float* A32 = (const float*)Av;
            int m = t >> 4, kk = (t & 15) * 4;
#pragma unroll
            for (int s = 0; s < 8; ++s) {
                int mm = m + s * 16;
                floatx4 f = *(const floatx4*)(A32 + (size_t)(m0 + mm) * NN + k0 + kk);
                u16x4 pk;
#pragma unroll
                for (int e = 0; e < 4; ++e) pk[e] = f32_bf16(f[e]);
                *(u16x4*)(&LA[mm * 72 + kk]) = pk;
            }
        } else {
            const float* A32 = (const float*)Av;
            int kr = t >> 5, mm = (t & 31) * 4;
#pragma unroll
            for (int s = 0; s < 8; ++s) {
                int kk = kr + s * 8;
                floatx4 f = *(const floatx4*)(A32 + (size_t)(k0 + kk) * NN + m0 + mm);
#pragma unroll
                for (int e = 0; e < 4; ++e) LA[(mm + e) * 72 + kk] = f32_bf16(f[e]);
            }
        }
        {
            int n = t >> 3, kk = (t & 7) * 8;
#pragma unroll
            for (int s = 0; s < 4; ++s) {
                int nn = n + s * 32;
                u16x8 d = *(const u16x8*)(Bt + (size_t)nn * NN + k0 + kk);
                *(u16x8*)(&LB[nn * 72 + kk]) = d;
            }
        }
        __syncthreads();
#pragma unroll
        for (int ks = 0; ks < 2; ++ks) {
            s16x8 af[4], bfr[4];
#pragma unroll
            for (int i = 0; i < 4; ++i) {
                int m = wy * 64 + i * 16 + l15;
                af[i] = *(const s16x8*)(&LA[m * 72 + ks * 32 + l4 * 8]);
                int n = wx * 64 + i * 16 + l15;
                bfr[i] = *(const s16x8*)(&LB[n * 72 + ks * 32 + l4 * 8]);
            }
#pragma unroll
            for (int i = 0; i < 4; ++i)
#pragma unroll
                for (int j = 0; j < 4; ++j)
                    acc[i][j] = __builtin_amdgcn_mfma_f32_16x16x32_bf16(
                        af[i], bfr[j], acc[i][j], 0, 0, 0);
        }
        __syncthreads();
    }
    float* Y = Ypart + (size_t)blockIdx.y * ((size_t)NN * DD);
#pragma unroll
    for (int i = 0; i < 4; ++i)
#pragma unroll
        for (int j = 0; j < 4; ++j) {
            int col = wx * 64 + j * 16 + l15;
#pragma unroll
            for (int r = 0; r < 4; ++r) {
                int row = wy * 64 + i * 16 + l4 * 4 + r;
                Y[(size_t)(m0 + row) * DD + col] = acc[i][j][r];
            }
        }
}

// ---------------------------------------------------------------------------
// gemm_small: Z[m][n] = (sum_s Ypart[s][m][:]) @ W  * (1/sums[m])
//   writes out32 fp32 [NN][DD] (if non-null) and/or outT bf16 [DD][NN].
// BM=64, k=128 (one staged tile), grid = NN/64 = 128, block=256.
// ---------------------------------------------------------------------------
__global__ __launch_bounds__(256) void gemm_small(const float* __restrict__ Ypart,
        const unsigned short* __restrict__ Wt, const float* __restrict__ sums,
        float* __restrict__ out32, unsigned short* __restrict__ outT) {
    __shared__ __align__(16) unsigned short LA[64 * 136];
    __shared__ __align__(16) unsigned short LB[128 * 136];
    int m0 = blockIdx.x * 64;
    int t = threadIdx.x;
    {
        int m = t >> 5, kk = (t & 31) * 4;
#pragma unroll
        for (int s8 = 0; s8 < 8; ++s8) {
            int mm = m + s8 * 8;
            floatx4 sum = {0.f, 0.f, 0.f, 0.f};
#pragma unroll
            for (int s = 0; s < 8; ++s)
                sum += *(const floatx4*)(Ypart + (size_t)s * ((size_t)NN * DD) +
                                         (size_t)(m0 + mm) * DD + kk);
            u16x4 pk;
#pragma unroll
            for (int e = 0; e < 4; ++e) pk[e] = f32_bf16(sum[e]);
            *(u16x4*)(&LA[mm * 136 + kk]) = pk;
        }
        int n = t >> 4, k8 = (t & 15) * 8;
#pragma unroll
        for (int s = 0; s < 8; ++s) {
            int nn = n + s * 16;
            *(u16x8*)(&LB[nn * 136 + k8]) = *(const u16x8*)(Wt + nn * 128 + k8);
        }
    }
    __syncthreads();
    int wid = t >> 6, lane = t & 63;
    int wy = wid >> 1, wx = wid & 1, l15 = lane & 15, l4 = lane >> 4;
    floatx4 acc[2][4] = {};
#pragma unroll
    for (int ks = 0; ks < 4; ++ks) {
        s16x8 af[2], bfr[4];
#pragma unroll
        for (int i = 0; i < 2; ++i)
            af[i] = *(const s16x8*)(&LA[(wy * 32 + i * 16 + l15) * 136 + ks * 32 + l4 * 8]);
#pragma unroll
        for (int j = 0; j < 4; ++j)
            bfr[j] = *(const s16x8*)(&LB[(wx * 64 + j * 16 + l15) * 136 + ks * 32 + l4 * 8]);
#pragma unroll
        for (int i = 0; i < 2; ++i)
#pragma unroll
            for (int j = 0; j < 4; ++j)
                acc[i][j] = __builtin_amdgcn_mfma_f32_16x16x32_bf16(
                    af[i], bfr[j], acc[i][j], 0, 0, 0);
    }
#pragma unroll
    for (int i = 0; i < 2; ++i)
#pragma unroll
        for (int j = 0; j < 4; ++j) {
            int col = wx * 64 + j * 16 + l15;
#pragma unroll
            for (int r = 0; r < 4; ++r) {
                int row = wy * 32 + i * 16 + l4 * 4 + r;
                int m = m0 + row;
                float val = acc[i][j][r] / sums[m];
                if (out32) out32[(size_t)m * DD + col] = val;
                if (outT) outT[(size_t)col * NN + m] = f32_bf16(val);
            }
        }
}

// ---------------------------------------------------------------------------
extern "C" void kernel_launch(void* const* d_in, const int* in_sizes, int n_in,
                              void* d_out, int out_size, void* d_ws, size_t ws_size,
                              hipStream_t stream) {
    const float* adj = (const float*)d_in[0];
    const float* uni = (const float*)d_in[1];
    const float* sub = (const float*)d_in[2];
    const float* ws1 = (const float*)d_in[3];
    const float* wu1 = (const float*)d_in[4];
    float* out = (float*)d_out;

    const size_t SZ_A16 = (size_t)NN * NN * 2;       // 128 MiB
    const size_t SZ_Y   = (size_t)8 * NN * DD * 4;   // 32 MiB (8 split-K slices)
    const size_t SZ_F   = (size_t)NN * DD * 2;       // 2 MiB
    const size_t SZ_W   = (size_t)128 * 128 * 2;
    const size_t SZ_V   = (size_t)NN * 4;

    size_t needA = 2 * SZ_A16 + SZ_Y + 6 * SZ_F + 2 * SZ_W + 2 * SZ_V;
    size_t needB = 1 * SZ_A16 + SZ_Y + 6 * SZ_F + 2 * SZ_W + 2 * SZ_V;
    int tier = (ws_size >= needA) ? 0 : ((ws_size >= needB) ? 1 : 2);

    char* p = (char*)d_ws;
    unsigned short* A16 = nullptr;
    unsigned short* AT16 = nullptr;
    if (tier == 0) { A16 = (unsigned short*)p; p += SZ_A16; }
    if (tier <= 1) { AT16 = (unsigned short*)p; p += SZ_A16; }
    float* Ypart = (float*)p; p += SZ_Y;
    unsigned short* F[6];
    for (int i = 0; i < 6; ++i) { F[i] = (unsigned short*)p; p += SZ_F; }
    unsigned short* Wst = (unsigned short*)p; p += SZ_W;
    unsigned short* Wut = (unsigned short*)p; p += SZ_W;
    float* rsum = (float*)p; p += SZ_V;
    float* csum = (float*)p; p += SZ_V;

    // --- preprocessing: one pass over adj does convert(s) + row/col sums ---
    hipMemsetAsync(rsum, 0, 2 * SZ_V, stream);   // rsum & csum contiguous
    if (tier == 0)
        convert_fused<<<dim3(128, 128), 256, 0, stream>>>(adj, AT16, A16, NN, NN, rsum, csum);
    else if (tier == 1)
        convert_fused<<<dim3(128, 128), 256, 0, stream>>>(adj, AT16, nullptr, NN, NN, rsum, csum);
    else
        convert_fused<<<dim3(128, 128), 256, 0, stream>>>(adj, nullptr, nullptr, NN, NN, rsum, csum);
    convert_fused<<<dim3(128, 2), 256, 0, stream>>>(uni, F[0], nullptr, NN, DD, nullptr, nullptr);
    convert_fused<<<dim3(128, 2), 256, 0, stream>>>(sub, F[1], nullptr, NN, DD, nullptr, nullptr);
    convert_fused<<<dim3(2, 2), 256, 0, stream>>>(ws1, Wst, nullptr, DD, DD, nullptr, nullptr);
    convert_fused<<<dim3(2, 2), 256, 0, stream>>>(wu1, Wut, nullptr, DD, DD, nullptr, nullptr);

    unsigned short* Ut[3] = {F[0], F[3], F[5]};
    unsigned short* St[3] = {F[1], F[2], F[4]};

    for (int pass = 0; pass < 3; ++pass) {
        // G2: Ys = adjT @ U_prev  (normalize by colsum, then @ w_s1)
        if (tier <= 1)
            gemm_big_bf16<<<dim3(64, 8), 256, 0, stream>>>(AT16, Ut[pass], Ypart);
        else
            gemm_big<2><<<dim3(64, 8), 256, 0, stream>>>(adj, Ut[pass], Ypart);
        if (pass < 2)
            gemm_small<<<128, 256, 0, stream>>>(Ypart, Wst, csum, nullptr, St[pass + 1]);
        else
            gemm_small<<<128, 256, 0, stream>>>(Ypart, Wst, csum, out, nullptr);

        // G1: Yu = adj @ S_prev  (normalize by rowsum, then @ w_u1)
        if (tier == 0)
            gemm_big_bf16<<<dim3(64, 8), 256, 0, stream>>>(A16, St[pass], Ypart);
        else
            gemm_big<1><<<dim3(64, 8), 256, 0, stream>>>(adj, St[pass], Ypart);
        if (pass < 2)
            gemm_small<<<128, 256, 0, stream>>>(Ypart, Wut, rsum, nullptr, Ut[pass + 1]);
        else
            gemm_small<<<128, 256, 0, stream>>>(Ypart, Wut, rsum, out + (size_t)NN * DD, nullptr);
    }
}